// Round 1
// baseline (2999.358 us; speedup 1.0000x reference)
//
#include <hip/hip_runtime.h>

typedef __bf16 bf16;
typedef __bf16 bf16x8 __attribute__((ext_vector_type(8)));
typedef float f32x4 __attribute__((ext_vector_type(4)));

#define D_MODEL 1024
#define D_STATE 16
#define D_CONV 4
#define D_INNER 2048
#define D_FF 4096
#define B_SZ 2
#define SEQ 1024
#define NTOK (B_SZ * SEQ)  // 2048 tokens

// ---------------------------------------------------------------- LayerNorm
__global__ __launch_bounds__(256) void ln_kernel(const float* __restrict__ x,
                                                 const float* __restrict__ g,
                                                 const float* __restrict__ b,
                                                 bf16* __restrict__ out) {
  int row = blockIdx.x;
  const float* xr = x + (size_t)row * D_MODEL;
  int t = threadIdx.x;
  float4 v = ((const float4*)xr)[t];
  float s = v.x + v.y + v.z + v.w;
  float s2 = v.x * v.x + v.y * v.y + v.z * v.z + v.w * v.w;
  for (int off = 32; off > 0; off >>= 1) {
    s += __shfl_down(s, off);
    s2 += __shfl_down(s2, off);
  }
  __shared__ float red[8];
  int wid = t >> 6, lane = t & 63;
  if (lane == 0) { red[wid] = s; red[4 + wid] = s2; }
  __syncthreads();
  if (t == 0) {
    float a = red[0] + red[1] + red[2] + red[3];
    float a2 = red[4] + red[5] + red[6] + red[7];
    red[0] = a * (1.0f / D_MODEL);
    red[1] = a2 * (1.0f / D_MODEL);
  }
  __syncthreads();
  float mean = red[0];
  float var = red[1] - mean * mean;
  float rs = rsqrtf(var + 1e-5f);
  float4 gg = ((const float4*)g)[t];
  float4 bb = ((const float4*)b)[t];
  bf16 o[4] __attribute__((aligned(8)));
  o[0] = (bf16)((v.x - mean) * rs * gg.x + bb.x);
  o[1] = (bf16)((v.y - mean) * rs * gg.y + bb.y);
  o[2] = (bf16)((v.z - mean) * rs * gg.z + bb.z);
  o[3] = (bf16)((v.w - mean) * rs * gg.w + bb.w);
  *(uint2*)&out[(size_t)row * D_MODEL + t * 4] = *(const uint2*)o;
}

// ------------------------------------------- transpose f32 [K][N] -> bf16 [N][K]
__global__ __launch_bounds__(256) void transpose_bf16_kernel(
    const float* __restrict__ W, bf16* __restrict__ Wt, int K, int N) {
  __shared__ float tile[32][33];
  int n0 = blockIdx.x * 32, k0 = blockIdx.y * 32;
  int t = threadIdx.x;
  int kr = t >> 3;
  int nc = (t & 7) * 4;
  float4 v = *(const float4*)&W[(size_t)(k0 + kr) * N + n0 + nc];
  tile[kr][nc + 0] = v.x;
  tile[kr][nc + 1] = v.y;
  tile[kr][nc + 2] = v.z;
  tile[kr][nc + 3] = v.w;
  __syncthreads();
  int nr = t >> 3;
  int kc = (t & 7) * 4;
  bf16 o[4] __attribute__((aligned(8)));
  o[0] = (bf16)tile[kc + 0][nr];
  o[1] = (bf16)tile[kc + 1][nr];
  o[2] = (bf16)tile[kc + 2][nr];
  o[3] = (bf16)tile[kc + 3][nr];
  *(uint2*)&Wt[(size_t)(n0 + nr) * K + k0 + kc] = *(const uint2*)o;
}

// ---------------------------------------------------- causal depthwise conv
__global__ __launch_bounds__(256) void conv_kernel(const float* __restrict__ xg,
                                                   const float* __restrict__ cw,
                                                   const float* __restrict__ cb,
                                                   bf16* __restrict__ xc) {
  int idx = blockIdx.x * 256 + threadIdx.x;  // (b,s,d)
  int d = idx & (D_INNER - 1);
  int s = (idx >> 11) & (SEQ - 1);
  int b = idx >> 21;
  const float* base = xg + (size_t)b * SEQ * (2 * D_INNER);
  float acc = cb[d];
#pragma unroll
  for (int j = 0; j < 4; j++) {
    int sp = s - 3 + j;
    if (sp >= 0) acc += base[(size_t)sp * (2 * D_INNER) + d] * cw[d * 4 + j];
  }
  xc[idx] = (bf16)acc;
}

// -------------------------------------------------------------- selective scan
__global__ __launch_bounds__(256) void scan_kernel(
    const bf16* __restrict__ Bm, const bf16* __restrict__ Cm,
    const float* __restrict__ delta, const float* __restrict__ xg,
    const float* __restrict__ A_log, const float* __restrict__ Dp,
    bf16* __restrict__ y) {
  int tid = blockIdx.x * 256 + threadIdx.x;  // (b,d,n)
  int n = tid & 15;
  int d = (tid >> 4) & (D_INNER - 1);
  int b = tid >> 15;
  float A = -__expf(A_log[d * D_STATE + n]);
  float dcoef = Dp[d];
  float h = 0.f;
  size_t bc = (size_t)b * SEQ * (D_INNER * D_STATE) + (size_t)d * D_STATE + n;
  size_t dB = (size_t)b * SEQ * D_INNER + d;
  size_t gB = (size_t)b * SEQ * (2 * D_INNER) + d;
  for (int s = 0; s < SEQ; s++) {
    float bm = (float)Bm[bc + (size_t)s * (D_INNER * D_STATE)];
    float cm = (float)Cm[bc + (size_t)s * (D_INNER * D_STATE)];
    float dl = delta[dB + (size_t)s * D_INNER];
    float xp = xg[gB + (size_t)s * (2 * D_INNER)];
    float a = __expf(dl * A);
    h = a * h + (dl * bm) * xp;
    float p = cm * h;
    p += __shfl_xor(p, 1);
    p += __shfl_xor(p, 2);
    p += __shfl_xor(p, 4);
    p += __shfl_xor(p, 8);
    if (n == 0) {
      float gt = xg[gB + D_INNER + (size_t)s * (2 * D_INNER)];
      float sig = 1.f / (1.f + __expf(-gt));
      float yv = (p + dcoef * xp) * (gt * sig);
      y[dB + (size_t)s * D_INNER] = (bf16)yv;
    }
  }
}

// ------------------------------------------------------------------- MFMA GEMM
// C[M,N] = A[M,K] (bf16, row-major) * Bt[N,K]^T (bf16) + bias, fused epilogue.
enum { EPI_PLAIN = 0, EPI_DT = 1, EPI_BF16 = 2, EPI_ADD = 3, EPI_GELU = 4 };

template <int EPI>
__global__ __launch_bounds__(256) void gemm_bf16(
    const bf16* __restrict__ A, const bf16* __restrict__ Bt,
    const float* __restrict__ bias, const float* __restrict__ extra,
    void* __restrict__ outv, int M, int N, int K) {
  __shared__ bf16 As[128 * 40];  // 128 rows, 32 k + pad->40 (80B stride, 16B aligned)
  __shared__ bf16 Bs[128 * 40];
  int t = threadIdx.x;
  int lane = t & 63, wid = t >> 6;
  int wm = wid & 1, wn = wid >> 1;   // 2x2 waves, each 64x64
  int l16 = lane & 15, quad = lane >> 4;
  int m0 = blockIdx.y * 128, n0 = blockIdx.x * 128;

  int srow = t >> 1, shalf = t & 1;  // 2 threads per row, 16 bf16 each
  const uint4* ga = (const uint4*)(A + (size_t)(m0 + srow) * K) + shalf * 2;
  const uint4* gb = (const uint4*)(Bt + (size_t)(n0 + srow) * K) + shalf * 2;
  uint4* la = (uint4*)&As[srow * 40 + shalf * 16];
  uint4* lb = (uint4*)&Bs[srow * 40 + shalf * 16];

  f32x4 acc[4][4] = {};
  for (int k0 = 0; k0 < K; k0 += 32) {
    uint4 a0 = ga[0], a1 = ga[1];
    uint4 b0 = gb[0], b1 = gb[1];
    __syncthreads();
    la[0] = a0; la[1] = a1;
    lb[0] = b0; lb[1] = b1;
    __syncthreads();
    bf16x8 af[4], bfr[4];
#pragma unroll
    for (int i = 0; i < 4; i++) {
      af[i]  = *(const bf16x8*)&As[(wm * 64 + i * 16 + l16) * 40 + quad * 8];
      bfr[i] = *(const bf16x8*)&Bs[(wn * 64 + i * 16 + l16) * 40 + quad * 8];
    }
#pragma unroll
    for (int mi = 0; mi < 4; mi++)
#pragma unroll
      for (int ni = 0; ni < 4; ni++)
        acc[mi][ni] = __builtin_amdgcn_mfma_f32_16x16x32_bf16(af[mi], bfr[ni],
                                                              acc[mi][ni], 0, 0, 0);
    ga += 4;
    gb += 4;
  }
  // epilogue: D row = quad*4+r, col = l16 (verified m89/m91 layout)
#pragma unroll
  for (int mi = 0; mi < 4; mi++) {
#pragma unroll
    for (int ni = 0; ni < 4; ni++) {
      int col = n0 + wn * 64 + ni * 16 + l16;
      int mrow0 = m0 + wm * 64 + mi * 16 + quad * 4;
#pragma unroll
      for (int r = 0; r < 4; r++) {
        int m = mrow0 + r;
        float v = acc[mi][ni][r] + bias[col];
        size_t o = (size_t)m * N + col;
        if (EPI == EPI_PLAIN) {
          ((float*)outv)[o] = v;
        } else if (EPI == EPI_DT) {
          ((float*)outv)[o] = (1.f / (1.f + __expf(-v))) * 0.099f + 0.001f;
        } else if (EPI == EPI_BF16) {
          ((bf16*)outv)[o] = (bf16)v;
        } else if (EPI == EPI_ADD) {
          ((float*)outv)[o] = v + extra[o];
        } else if (EPI == EPI_GELU) {
          ((bf16*)outv)[o] = (bf16)(0.5f * v * (1.f + erff(v * 0.70710678118f)));
        }
      }
    }
  }
}

// ---------------------------------------------------------------------- launch
extern "C" void kernel_launch(void* const* d_in, const int* in_sizes, int n_in,
                              void* d_out, int out_size, void* d_ws, size_t ws_size,
                              hipStream_t stream) {
  const float* x      = (const float*)d_in[0];
  const float* ln1_g  = (const float*)d_in[1];
  const float* ln1_b  = (const float*)d_in[2];
  const float* W_in   = (const float*)d_in[3];
  const float* b_in   = (const float*)d_in[4];
  const float* conv_w = (const float*)d_in[5];
  const float* conv_b = (const float*)d_in[6];
  const float* A_log  = (const float*)d_in[7];
  const float* W_B    = (const float*)d_in[8];
  const float* b_B    = (const float*)d_in[9];
  const float* W_C    = (const float*)d_in[10];
  const float* b_C    = (const float*)d_in[11];
  const float* Dp     = (const float*)d_in[12];
  const float* W_dt   = (const float*)d_in[13];
  const float* b_dt   = (const float*)d_in[14];
  const float* W_out  = (const float*)d_in[15];
  const float* b_out  = (const float*)d_in[16];
  const float* ln2_g  = (const float*)d_in[17];
  const float* ln2_b  = (const float*)d_in[18];
  const float* W1     = (const float*)d_in[19];
  const float* b1     = (const float*)d_in[20];
  const float* W2     = (const float*)d_in[21];
  const float* b2     = (const float*)d_in[22];
  float* out = (float*)d_out;

  char* ws = (char*)d_ws;
  size_t off = 0;
  auto alloc = [&](size_t bytes) -> void* {
    void* p = ws + off;
    off += (bytes + 255) & ~(size_t)255;
    return p;
  };
  bf16*  xn_bf  = (bf16*)alloc((size_t)NTOK * D_MODEL * 2);
  float* xg     = (float*)alloc((size_t)NTOK * 2 * D_INNER * 4);
  bf16*  xc_bf  = (bf16*)alloc((size_t)NTOK * D_INNER * 2);
  float* delta  = (float*)alloc((size_t)NTOK * D_INNER * 4);
  bf16*  Bm     = (bf16*)alloc((size_t)NTOK * D_INNER * D_STATE * 2);
  bf16*  Cm     = (bf16*)alloc((size_t)NTOK * D_INNER * D_STATE * 2);
  bf16*  y_bf   = (bf16*)alloc((size_t)NTOK * D_INNER * 2);
  float* x2     = (float*)alloc((size_t)NTOK * D_MODEL * 4);
  bf16*  xn2_bf = (bf16*)alloc((size_t)NTOK * D_MODEL * 2);
  bf16*  h1_bf  = (bf16*)alloc((size_t)NTOK * D_FF * 2);
  bf16*  wt     = (bf16*)alloc((size_t)D_INNER * (D_INNER * D_STATE) * 2); // reused

  dim3 blk(256);

  // 1. LN1
  ln_kernel<<<NTOK, blk, 0, stream>>>(x, ln1_g, ln1_b, xn_bf);
  // 2. in-projection -> xg (x_proj | gate)
  transpose_bf16_kernel<<<dim3((2 * D_INNER) / 32, D_MODEL / 32), blk, 0, stream>>>(
      W_in, wt, D_MODEL, 2 * D_INNER);
  gemm_bf16<EPI_PLAIN><<<dim3((2 * D_INNER) / 128, NTOK / 128), blk, 0, stream>>>(
      xn_bf, wt, b_in, nullptr, xg, NTOK, 2 * D_INNER, D_MODEL);
  // 3. causal depthwise conv -> xc
  conv_kernel<<<(NTOK * D_INNER) / 256, blk, 0, stream>>>(xg, conv_w, conv_b, xc_bf);
  // 4. delta
  transpose_bf16_kernel<<<dim3(D_INNER / 32, D_INNER / 32), blk, 0, stream>>>(
      W_dt, wt, D_INNER, D_INNER);
  gemm_bf16<EPI_DT><<<dim3(D_INNER / 128, NTOK / 128), blk, 0, stream>>>(
      xc_bf, wt, b_dt, nullptr, delta, NTOK, D_INNER, D_INNER);
  // 5. B projection
  transpose_bf16_kernel<<<dim3((D_INNER * D_STATE) / 32, D_INNER / 32), blk, 0, stream>>>(
      W_B, wt, D_INNER, D_INNER * D_STATE);
  gemm_bf16<EPI_BF16><<<dim3((D_INNER * D_STATE) / 128, NTOK / 128), blk, 0, stream>>>(
      xc_bf, wt, b_B, nullptr, Bm, NTOK, D_INNER * D_STATE, D_INNER);
  // 6. C projection (reuse wt after GEMM_B — stream-ordered)
  transpose_bf16_kernel<<<dim3((D_INNER * D_STATE) / 32, D_INNER / 32), blk, 0, stream>>>(
      W_C, wt, D_INNER, D_INNER * D_STATE);
  gemm_bf16<EPI_BF16><<<dim3((D_INNER * D_STATE) / 128, NTOK / 128), blk, 0, stream>>>(
      xc_bf, wt, b_C, nullptr, Cm, NTOK, D_INNER * D_STATE, D_INNER);
  // 7. selective scan (fused +Dp*x_proj and *silu(gate))
  scan_kernel<<<(B_SZ * D_INNER * D_STATE) / 256, blk, 0, stream>>>(
      Bm, Cm, delta, xg, A_log, Dp, y_bf);
  // 8. out projection + residual
  transpose_bf16_kernel<<<dim3(D_MODEL / 32, D_INNER / 32), blk, 0, stream>>>(
      W_out, wt, D_INNER, D_MODEL);
  gemm_bf16<EPI_ADD><<<dim3(D_MODEL / 128, NTOK / 128), blk, 0, stream>>>(
      y_bf, wt, b_out, x, x2, NTOK, D_MODEL, D_INNER);
  // 9. LN2
  ln_kernel<<<NTOK, blk, 0, stream>>>(x2, ln2_g, ln2_b, xn2_bf);
  // 10. FFN up + exact GELU
  transpose_bf16_kernel<<<dim3(D_FF / 32, D_MODEL / 32), blk, 0, stream>>>(
      W1, wt, D_MODEL, D_FF);
  gemm_bf16<EPI_GELU><<<dim3(D_FF / 128, NTOK / 128), blk, 0, stream>>>(
      xn2_bf, wt, b1, nullptr, h1_bf, NTOK, D_FF, D_MODEL);
  // 11. FFN down + residual -> out
  transpose_bf16_kernel<<<dim3(D_MODEL / 32, D_FF / 32), blk, 0, stream>>>(
      W2, wt, D_FF, D_MODEL);
  gemm_bf16<EPI_ADD><<<dim3(D_MODEL / 128, NTOK / 128), blk, 0, stream>>>(
      h1_bf, wt, b2, x2, out, NTOK, D_MODEL, D_FF);
}

// Round 2
// 1999.352 us; speedup vs baseline: 1.5002x; 1.5002x over previous
//
#include <hip/hip_runtime.h>

typedef __bf16 bf16;
typedef __bf16 bf16x8 __attribute__((ext_vector_type(8)));
typedef float f32x4 __attribute__((ext_vector_type(4)));

#define D_MODEL 1024
#define D_STATE 16
#define D_CONV 4
#define D_INNER 2048
#define D_FF 4096
#define B_SZ 2
#define SEQ 1024
#define NTOK (B_SZ * SEQ)  // 2048 tokens
#define NCHUNK 16
#define CLEN (SEQ / NCHUNK)  // 64

// ---------------------------------------------------------------- LayerNorm
__global__ __launch_bounds__(256) void ln_kernel(const float* __restrict__ x,
                                                 const float* __restrict__ g,
                                                 const float* __restrict__ b,
                                                 bf16* __restrict__ out) {
  int row = blockIdx.x;
  const float* xr = x + (size_t)row * D_MODEL;
  int t = threadIdx.x;
  float4 v = ((const float4*)xr)[t];
  float s = v.x + v.y + v.z + v.w;
  float s2 = v.x * v.x + v.y * v.y + v.z * v.z + v.w * v.w;
  for (int off = 32; off > 0; off >>= 1) {
    s += __shfl_down(s, off);
    s2 += __shfl_down(s2, off);
  }
  __shared__ float red[8];
  int wid = t >> 6, lane = t & 63;
  if (lane == 0) { red[wid] = s; red[4 + wid] = s2; }
  __syncthreads();
  if (t == 0) {
    float a = red[0] + red[1] + red[2] + red[3];
    float a2 = red[4] + red[5] + red[6] + red[7];
    red[0] = a * (1.0f / D_MODEL);
    red[1] = a2 * (1.0f / D_MODEL);
  }
  __syncthreads();
  float mean = red[0];
  float var = red[1] - mean * mean;
  float rs = rsqrtf(var + 1e-5f);
  float4 gg = ((const float4*)g)[t];
  float4 bb = ((const float4*)b)[t];
  bf16 o[4] __attribute__((aligned(8)));
  o[0] = (bf16)((v.x - mean) * rs * gg.x + bb.x);
  o[1] = (bf16)((v.y - mean) * rs * gg.y + bb.y);
  o[2] = (bf16)((v.z - mean) * rs * gg.z + bb.z);
  o[3] = (bf16)((v.w - mean) * rs * gg.w + bb.w);
  *(uint2*)&out[(size_t)row * D_MODEL + t * 4] = *(const uint2*)o;
}

// ------------------------------------------- transpose f32 [K][N] -> bf16 [N][K]
__global__ __launch_bounds__(256) void transpose_bf16_kernel(
    const float* __restrict__ W, bf16* __restrict__ Wt, int K, int N) {
  __shared__ float tile[32][33];
  int n0 = blockIdx.x * 32, k0 = blockIdx.y * 32;
  int t = threadIdx.x;
  int kr = t >> 3;
  int nc = (t & 7) * 4;
  float4 v = *(const float4*)&W[(size_t)(k0 + kr) * N + n0 + nc];
  tile[kr][nc + 0] = v.x;
  tile[kr][nc + 1] = v.y;
  tile[kr][nc + 2] = v.z;
  tile[kr][nc + 3] = v.w;
  __syncthreads();
  int nr = t >> 3;
  int kc = (t & 7) * 4;
  bf16 o[4] __attribute__((aligned(8)));
  o[0] = (bf16)tile[kc + 0][nr];
  o[1] = (bf16)tile[kc + 1][nr];
  o[2] = (bf16)tile[kc + 2][nr];
  o[3] = (bf16)tile[kc + 3][nr];
  *(uint2*)&Wt[(size_t)(n0 + nr) * K + k0 + kc] = *(const uint2*)o;
}

// ---------------------------------------------------- causal depthwise conv
__global__ __launch_bounds__(256) void conv_kernel(const float* __restrict__ xg,
                                                   const float* __restrict__ cw,
                                                   const float* __restrict__ cb,
                                                   bf16* __restrict__ xc) {
  int idx = blockIdx.x * 256 + threadIdx.x;  // (b,s,d)
  int d = idx & (D_INNER - 1);
  int s = (idx >> 11) & (SEQ - 1);
  int b = idx >> 21;
  const float* base = xg + (size_t)b * SEQ * (2 * D_INNER);
  float acc = cb[d];
#pragma unroll
  for (int j = 0; j < 4; j++) {
    int sp = s - 3 + j;
    if (sp >= 0) acc += base[(size_t)sp * (2 * D_INNER) + d] * cw[d * 4 + j];
  }
  xc[idx] = (bf16)acc;
}

// ----------------------------------------------- selective scan, chunk-parallel
// Recurrence h_s = a_s h_{s-1} + dl*bm*xp is linear -> exact chunk decomposition.
// Phase 1: per chunk from h=0, record P = prod(a), H = local final h.
// Phase 2: tiny 16-step carry scan over chunks -> h_start per chunk.
// Phase 3: re-run chunk recurrence seeded with h_start, emit y (Dp/silu fused).

// tid bits: [0:3]=n, [4:14]=d, [15:18]=chunk, [19]=b
__global__ __launch_bounds__(256) void scan_phase1(
    const bf16* __restrict__ Bm, const float* __restrict__ delta,
    const float* __restrict__ xg, const float* __restrict__ A_log,
    float* __restrict__ Pprod, float* __restrict__ Hloc) {
  int tid = blockIdx.x * 256 + threadIdx.x;
  int n = tid & 15;
  int d = (tid >> 4) & (D_INNER - 1);
  int c = (tid >> 15) & (NCHUNK - 1);
  int b = tid >> 19;
  float A = -__expf(A_log[d * D_STATE + n]);
  int s0 = c * CLEN;
  size_t bc = ((size_t)(b * SEQ + s0) * D_INNER + d) * D_STATE + n;
  size_t dB = (size_t)(b * SEQ + s0) * D_INNER + d;
  size_t gB = (size_t)(b * SEQ + s0) * (2 * D_INNER) + d;
  float h = 0.f, P = 1.f;
  for (int s = 0; s < CLEN; s++) {
    float bm = (float)Bm[bc + (size_t)s * (D_INNER * D_STATE)];
    float dl = delta[dB + (size_t)s * D_INNER];
    float xp = xg[gB + (size_t)s * (2 * D_INNER)];
    float a = __expf(dl * A);
    h = a * h + (dl * bm) * xp;
    P *= a;
  }
  size_t o = ((size_t)((b * NCHUNK + c) * D_INNER) + d) * D_STATE + n;
  Pprod[o] = P;
  Hloc[o] = h;
}

// tid bits: [0:3]=n, [4:14]=d, [15]=b
__global__ __launch_bounds__(256) void scan_phase2(
    const float* __restrict__ Pprod, const float* __restrict__ Hloc,
    float* __restrict__ Hstart) {
  int tid = blockIdx.x * 256 + threadIdx.x;
  int n = tid & 15;
  int d = (tid >> 4) & (D_INNER - 1);
  int b = tid >> 15;
  float h = 0.f;
#pragma unroll
  for (int c = 0; c < NCHUNK; c++) {
    size_t o = ((size_t)((b * NCHUNK + c) * D_INNER) + d) * D_STATE + n;
    Hstart[o] = h;
    h = Pprod[o] * h + Hloc[o];
  }
}

__global__ __launch_bounds__(256) void scan_phase3(
    const bf16* __restrict__ Bm, const bf16* __restrict__ Cm,
    const float* __restrict__ delta, const float* __restrict__ xg,
    const float* __restrict__ A_log, const float* __restrict__ Dp,
    const float* __restrict__ Hstart, bf16* __restrict__ y) {
  int tid = blockIdx.x * 256 + threadIdx.x;
  int n = tid & 15;
  int d = (tid >> 4) & (D_INNER - 1);
  int c = (tid >> 15) & (NCHUNK - 1);
  int b = tid >> 19;
  float A = -__expf(A_log[d * D_STATE + n]);
  float dcoef = Dp[d];
  int s0 = c * CLEN;
  size_t bc = ((size_t)(b * SEQ + s0) * D_INNER + d) * D_STATE + n;
  size_t dB = (size_t)(b * SEQ + s0) * D_INNER + d;
  size_t gB = (size_t)(b * SEQ + s0) * (2 * D_INNER) + d;
  float h = Hstart[((size_t)((b * NCHUNK + c) * D_INNER) + d) * D_STATE + n];
  for (int s = 0; s < CLEN; s++) {
    float bm = (float)Bm[bc + (size_t)s * (D_INNER * D_STATE)];
    float cm = (float)Cm[bc + (size_t)s * (D_INNER * D_STATE)];
    float dl = delta[dB + (size_t)s * D_INNER];
    float xp = xg[gB + (size_t)s * (2 * D_INNER)];
    float a = __expf(dl * A);
    h = a * h + (dl * bm) * xp;
    float p = cm * h;
    p += __shfl_xor(p, 1);
    p += __shfl_xor(p, 2);
    p += __shfl_xor(p, 4);
    p += __shfl_xor(p, 8);
    if (n == 0) {
      float gt = xg[gB + D_INNER + (size_t)s * (2 * D_INNER)];
      float sig = 1.f / (1.f + __expf(-gt));
      float yv = (p + dcoef * xp) * (gt * sig);
      y[dB + (size_t)s * D_INNER] = (bf16)yv;
    }
  }
}

// ------------------------------------------------------------------- MFMA GEMM
// C[M,N] = A[M,K] (bf16, row-major) * Bt[N,K]^T (bf16) + bias, fused epilogue.
enum { EPI_PLAIN = 0, EPI_DT = 1, EPI_BF16 = 2, EPI_ADD = 3, EPI_GELU = 4 };

template <int EPI>
__global__ __launch_bounds__(256) void gemm_bf16(
    const bf16* __restrict__ A, const bf16* __restrict__ Bt,
    const float* __restrict__ bias, const float* __restrict__ extra,
    void* __restrict__ outv, int M, int N, int K) {
  __shared__ bf16 As[128 * 40];  // 128 rows, 32 k + pad->40 (80B stride, 16B aligned)
  __shared__ bf16 Bs[128 * 40];
  int t = threadIdx.x;
  int lane = t & 63, wid = t >> 6;
  int wm = wid & 1, wn = wid >> 1;   // 2x2 waves, each 64x64
  int l16 = lane & 15, quad = lane >> 4;
  int m0 = blockIdx.y * 128, n0 = blockIdx.x * 128;

  int srow = t >> 1, shalf = t & 1;  // 2 threads per row, 16 bf16 each
  const uint4* ga = (const uint4*)(A + (size_t)(m0 + srow) * K) + shalf * 2;
  const uint4* gb = (const uint4*)(Bt + (size_t)(n0 + srow) * K) + shalf * 2;
  uint4* la = (uint4*)&As[srow * 40 + shalf * 16];
  uint4* lb = (uint4*)&Bs[srow * 40 + shalf * 16];

  f32x4 acc[4][4] = {};
  for (int k0 = 0; k0 < K; k0 += 32) {
    uint4 a0 = ga[0], a1 = ga[1];
    uint4 b0 = gb[0], b1 = gb[1];
    __syncthreads();
    la[0] = a0; la[1] = a1;
    lb[0] = b0; lb[1] = b1;
    __syncthreads();
    bf16x8 af[4], bfr[4];
#pragma unroll
    for (int i = 0; i < 4; i++) {
      af[i]  = *(const bf16x8*)&As[(wm * 64 + i * 16 + l16) * 40 + quad * 8];
      bfr[i] = *(const bf16x8*)&Bs[(wn * 64 + i * 16 + l16) * 40 + quad * 8];
    }
#pragma unroll
    for (int mi = 0; mi < 4; mi++)
#pragma unroll
      for (int ni = 0; ni < 4; ni++)
        acc[mi][ni] = __builtin_amdgcn_mfma_f32_16x16x32_bf16(af[mi], bfr[ni],
                                                              acc[mi][ni], 0, 0, 0);
    ga += 4;
    gb += 4;
  }
  // epilogue: D row = quad*4+r, col = l16 (verified m89/m91 layout)
#pragma unroll
  for (int mi = 0; mi < 4; mi++) {
#pragma unroll
    for (int ni = 0; ni < 4; ni++) {
      int col = n0 + wn * 64 + ni * 16 + l16;
      int mrow0 = m0 + wm * 64 + mi * 16 + quad * 4;
#pragma unroll
      for (int r = 0; r < 4; r++) {
        int m = mrow0 + r;
        float v = acc[mi][ni][r] + bias[col];
        size_t o = (size_t)m * N + col;
        if (EPI == EPI_PLAIN) {
          ((float*)outv)[o] = v;
        } else if (EPI == EPI_DT) {
          ((float*)outv)[o] = (1.f / (1.f + __expf(-v))) * 0.099f + 0.001f;
        } else if (EPI == EPI_BF16) {
          ((bf16*)outv)[o] = (bf16)v;
        } else if (EPI == EPI_ADD) {
          ((float*)outv)[o] = v + extra[o];
        } else if (EPI == EPI_GELU) {
          ((bf16*)outv)[o] = (bf16)(0.5f * v * (1.f + erff(v * 0.70710678118f)));
        }
      }
    }
  }
}

// ---------------------------------------------------------------------- launch
extern "C" void kernel_launch(void* const* d_in, const int* in_sizes, int n_in,
                              void* d_out, int out_size, void* d_ws, size_t ws_size,
                              hipStream_t stream) {
  const float* x      = (const float*)d_in[0];
  const float* ln1_g  = (const float*)d_in[1];
  const float* ln1_b  = (const float*)d_in[2];
  const float* W_in   = (const float*)d_in[3];
  const float* b_in   = (const float*)d_in[4];
  const float* conv_w = (const float*)d_in[5];
  const float* conv_b = (const float*)d_in[6];
  const float* A_log  = (const float*)d_in[7];
  const float* W_B    = (const float*)d_in[8];
  const float* b_B    = (const float*)d_in[9];
  const float* W_C    = (const float*)d_in[10];
  const float* b_C    = (const float*)d_in[11];
  const float* Dp     = (const float*)d_in[12];
  const float* W_dt   = (const float*)d_in[13];
  const float* b_dt   = (const float*)d_in[14];
  const float* W_out  = (const float*)d_in[15];
  const float* b_out  = (const float*)d_in[16];
  const float* ln2_g  = (const float*)d_in[17];
  const float* ln2_b  = (const float*)d_in[18];
  const float* W1     = (const float*)d_in[19];
  const float* b1     = (const float*)d_in[20];
  const float* W2     = (const float*)d_in[21];
  const float* b2     = (const float*)d_in[22];
  float* out = (float*)d_out;

  char* ws = (char*)d_ws;
  size_t off = 0;
  auto alloc = [&](size_t bytes) -> void* {
    void* p = ws + off;
    off += (bytes + 255) & ~(size_t)255;
    return p;
  };
  bf16*  xn_bf  = (bf16*)alloc((size_t)NTOK * D_MODEL * 2);
  float* xg     = (float*)alloc((size_t)NTOK * 2 * D_INNER * 4);
  bf16*  xc_bf  = (bf16*)alloc((size_t)NTOK * D_INNER * 2);
  float* delta  = (float*)alloc((size_t)NTOK * D_INNER * 4);
  bf16*  Bm     = (bf16*)alloc((size_t)NTOK * D_INNER * D_STATE * 2);
  bf16*  Cm     = (bf16*)alloc((size_t)NTOK * D_INNER * D_STATE * 2);
  bf16*  y_bf   = (bf16*)alloc((size_t)NTOK * D_INNER * 2);
  float* x2     = (float*)alloc((size_t)NTOK * D_MODEL * 4);
  bf16*  xn2_bf = (bf16*)alloc((size_t)NTOK * D_MODEL * 2);
  bf16*  h1_bf  = (bf16*)alloc((size_t)NTOK * D_FF * 2);
  float* Pprod  = (float*)alloc((size_t)B_SZ * NCHUNK * D_INNER * D_STATE * 4);
  float* Hloc   = (float*)alloc((size_t)B_SZ * NCHUNK * D_INNER * D_STATE * 4);
  float* Hstart = (float*)alloc((size_t)B_SZ * NCHUNK * D_INNER * D_STATE * 4);
  bf16*  wt     = (bf16*)alloc((size_t)D_INNER * (D_INNER * D_STATE) * 2); // reused

  dim3 blk(256);

  // 1. LN1
  ln_kernel<<<NTOK, blk, 0, stream>>>(x, ln1_g, ln1_b, xn_bf);
  // 2. in-projection -> xg (x_proj | gate)
  transpose_bf16_kernel<<<dim3((2 * D_INNER) / 32, D_MODEL / 32), blk, 0, stream>>>(
      W_in, wt, D_MODEL, 2 * D_INNER);
  gemm_bf16<EPI_PLAIN><<<dim3((2 * D_INNER) / 128, NTOK / 128), blk, 0, stream>>>(
      xn_bf, wt, b_in, nullptr, xg, NTOK, 2 * D_INNER, D_MODEL);
  // 3. causal depthwise conv -> xc
  conv_kernel<<<(NTOK * D_INNER) / 256, blk, 0, stream>>>(xg, conv_w, conv_b, xc_bf);
  // 4. delta
  transpose_bf16_kernel<<<dim3(D_INNER / 32, D_INNER / 32), blk, 0, stream>>>(
      W_dt, wt, D_INNER, D_INNER);
  gemm_bf16<EPI_DT><<<dim3(D_INNER / 128, NTOK / 128), blk, 0, stream>>>(
      xc_bf, wt, b_dt, nullptr, delta, NTOK, D_INNER, D_INNER);
  // 5. B projection
  transpose_bf16_kernel<<<dim3((D_INNER * D_STATE) / 32, D_INNER / 32), blk, 0, stream>>>(
      W_B, wt, D_INNER, D_INNER * D_STATE);
  gemm_bf16<EPI_BF16><<<dim3((D_INNER * D_STATE) / 128, NTOK / 128), blk, 0, stream>>>(
      xc_bf, wt, b_B, nullptr, Bm, NTOK, D_INNER * D_STATE, D_INNER);
  // 6. C projection (reuse wt after GEMM_B — stream-ordered)
  transpose_bf16_kernel<<<dim3((D_INNER * D_STATE) / 32, D_INNER / 32), blk, 0, stream>>>(
      W_C, wt, D_INNER, D_INNER * D_STATE);
  gemm_bf16<EPI_BF16><<<dim3((D_INNER * D_STATE) / 128, NTOK / 128), blk, 0, stream>>>(
      xc_bf, wt, b_C, nullptr, Cm, NTOK, D_INNER * D_STATE, D_INNER);
  // 7. selective scan, chunk-parallel (fused +Dp*x_proj and *silu(gate))
  scan_phase1<<<(B_SZ * NCHUNK * D_INNER * D_STATE) / 256, blk, 0, stream>>>(
      Bm, delta, xg, A_log, Pprod, Hloc);
  scan_phase2<<<(B_SZ * D_INNER * D_STATE) / 256, blk, 0, stream>>>(
      Pprod, Hloc, Hstart);
  scan_phase3<<<(B_SZ * NCHUNK * D_INNER * D_STATE) / 256, blk, 0, stream>>>(
      Bm, Cm, delta, xg, A_log, Dp, Hstart, y_bf);
  // 8. out projection + residual
  transpose_bf16_kernel<<<dim3(D_MODEL / 32, D_INNER / 32), blk, 0, stream>>>(
      W_out, wt, D_INNER, D_MODEL);
  gemm_bf16<EPI_ADD><<<dim3(D_MODEL / 128, NTOK / 128), blk, 0, stream>>>(
      y_bf, wt, b_out, x, x2, NTOK, D_MODEL, D_INNER);
  // 9. LN2
  ln_kernel<<<NTOK, blk, 0, stream>>>(x2, ln2_g, ln2_b, xn2_bf);
  // 10. FFN up + exact GELU
  transpose_bf16_kernel<<<dim3(D_FF / 32, D_MODEL / 32), blk, 0, stream>>>(
      W1, wt, D_MODEL, D_FF);
  gemm_bf16<EPI_GELU><<<dim3(D_FF / 128, NTOK / 128), blk, 0, stream>>>(
      xn2_bf, wt, b1, nullptr, h1_bf, NTOK, D_FF, D_MODEL);
  // 11. FFN down + residual -> out
  transpose_bf16_kernel<<<dim3(D_MODEL / 32, D_FF / 32), blk, 0, stream>>>(
      W2, wt, D_FF, D_MODEL);
  gemm_bf16<EPI_ADD><<<dim3(D_MODEL / 128, NTOK / 128), blk, 0, stream>>>(
      h1_bf, wt, b2, x2, out, NTOK, D_MODEL, D_FF);
}

// Round 3
// 1884.443 us; speedup vs baseline: 1.5916x; 1.0610x over previous
//
#include <hip/hip_runtime.h>

typedef __bf16 bf16;
typedef __bf16 bf16x8 __attribute__((ext_vector_type(8)));
typedef float f32x4 __attribute__((ext_vector_type(4)));

#define D_MODEL 1024
#define D_STATE 16
#define D_CONV 4
#define D_INNER 2048
#define D_FF 4096
#define B_SZ 2
#define SEQ 1024
#define NTOK (B_SZ * SEQ)  // 2048 tokens
#define NCHUNK 16
#define CLEN (SEQ / NCHUNK)  // 64

// async global->LDS, 16B per lane; LDS dest = wave-uniform base + lane*16
#define GLOAD_LDS16(gptr, ldsptr)                                            \
  __builtin_amdgcn_global_load_lds(                                          \
      (const __attribute__((address_space(1))) unsigned int*)(gptr),         \
      (__attribute__((address_space(3))) unsigned int*)(ldsptr), 16, 0, 0)

// ---------------------------------------------------------------- LayerNorm
__global__ __launch_bounds__(256) void ln_kernel(const float* __restrict__ x,
                                                 const float* __restrict__ g,
                                                 const float* __restrict__ b,
                                                 bf16* __restrict__ out) {
  int row = blockIdx.x;
  const float* xr = x + (size_t)row * D_MODEL;
  int t = threadIdx.x;
  float4 v = ((const float4*)xr)[t];
  float s = v.x + v.y + v.z + v.w;
  float s2 = v.x * v.x + v.y * v.y + v.z * v.z + v.w * v.w;
  for (int off = 32; off > 0; off >>= 1) {
    s += __shfl_down(s, off);
    s2 += __shfl_down(s2, off);
  }
  __shared__ float red[8];
  int wid = t >> 6, lane = t & 63;
  if (lane == 0) { red[wid] = s; red[4 + wid] = s2; }
  __syncthreads();
  if (t == 0) {
    float a = red[0] + red[1] + red[2] + red[3];
    float a2 = red[4] + red[5] + red[6] + red[7];
    red[0] = a * (1.0f / D_MODEL);
    red[1] = a2 * (1.0f / D_MODEL);
  }
  __syncthreads();
  float mean = red[0];
  float var = red[1] - mean * mean;
  float rs = rsqrtf(var + 1e-5f);
  float4 gg = ((const float4*)g)[t];
  float4 bb = ((const float4*)b)[t];
  bf16 o[4] __attribute__((aligned(8)));
  o[0] = (bf16)((v.x - mean) * rs * gg.x + bb.x);
  o[1] = (bf16)((v.y - mean) * rs * gg.y + bb.y);
  o[2] = (bf16)((v.z - mean) * rs * gg.z + bb.z);
  o[3] = (bf16)((v.w - mean) * rs * gg.w + bb.w);
  *(uint2*)&out[(size_t)row * D_MODEL + t * 4] = *(const uint2*)o;
}

// ------------------------------------------- transpose f32 [K][N] -> bf16 [N][K]
// 64x64 tile per 256-thread block, fully coalesced 128B-row stores.
__global__ __launch_bounds__(256) void transpose_bf16_kernel(
    const float* __restrict__ W, bf16* __restrict__ Wt, int K, int N) {
  __shared__ float tile[64][65];
  int n0 = blockIdx.x * 64, k0 = blockIdx.y * 64;
  int t = threadIdx.x;
  int kr = t >> 4;          // 0..15
  int nc = (t & 15) * 4;    // 0..60
#pragma unroll
  for (int g = 0; g < 4; g++) {
    float4 v = *(const float4*)&W[(size_t)(k0 + kr + g * 16) * N + n0 + nc];
    tile[kr + g * 16][nc + 0] = v.x;
    tile[kr + g * 16][nc + 1] = v.y;
    tile[kr + g * 16][nc + 2] = v.z;
    tile[kr + g * 16][nc + 3] = v.w;
  }
  __syncthreads();
  int nr = t >> 3;          // 0..31
  int kc = (t & 7) * 8;     // 0..56
#pragma unroll
  for (int p = 0; p < 2; p++) {
    int n = nr + p * 32;
    bf16 o[8] __attribute__((aligned(16)));
#pragma unroll
    for (int i = 0; i < 8; i++) o[i] = (bf16)tile[kc + i][n];
    *(uint4*)&Wt[(size_t)(n0 + n) * K + k0 + kc] = *(const uint4*)o;
  }
}

// ---------------------------------------------------- causal depthwise conv
__global__ __launch_bounds__(256) void conv_kernel(const float* __restrict__ xg,
                                                   const float* __restrict__ cw,
                                                   const float* __restrict__ cb,
                                                   bf16* __restrict__ xc) {
  int idx = blockIdx.x * 256 + threadIdx.x;  // (b,s,d)
  int d = idx & (D_INNER - 1);
  int s = (idx >> 11) & (SEQ - 1);
  int b = idx >> 21;
  const float* base = xg + (size_t)b * SEQ * (2 * D_INNER);
  float acc = cb[d];
#pragma unroll
  for (int j = 0; j < 4; j++) {
    int sp = s - 3 + j;
    if (sp >= 0) acc += base[(size_t)sp * (2 * D_INNER) + d] * cw[d * 4 + j];
  }
  xc[idx] = (bf16)acc;
}

// ----------------------------------------------- selective scan, chunk-parallel
__global__ __launch_bounds__(256) void scan_phase1(
    const bf16* __restrict__ Bm, const float* __restrict__ delta,
    const float* __restrict__ xg, const float* __restrict__ A_log,
    float* __restrict__ Pprod, float* __restrict__ Hloc) {
  int tid = blockIdx.x * 256 + threadIdx.x;
  int n = tid & 15;
  int d = (tid >> 4) & (D_INNER - 1);
  int c = (tid >> 15) & (NCHUNK - 1);
  int b = tid >> 19;
  float A = -__expf(A_log[d * D_STATE + n]);
  int s0 = c * CLEN;
  size_t bc = ((size_t)(b * SEQ + s0) * D_INNER + d) * D_STATE + n;
  size_t dB = (size_t)(b * SEQ + s0) * D_INNER + d;
  size_t gB = (size_t)(b * SEQ + s0) * (2 * D_INNER) + d;
  float h = 0.f, P = 1.f;
  for (int s = 0; s < CLEN; s++) {
    float bm = (float)Bm[bc + (size_t)s * (D_INNER * D_STATE)];
    float dl = delta[dB + (size_t)s * D_INNER];
    float xp = xg[gB + (size_t)s * (2 * D_INNER)];
    float a = __expf(dl * A);
    h = a * h + (dl * bm) * xp;
    P *= a;
  }
  size_t o = ((size_t)((b * NCHUNK + c) * D_INNER) + d) * D_STATE + n;
  Pprod[o] = P;
  Hloc[o] = h;
}

__global__ __launch_bounds__(256) void scan_phase2(
    const float* __restrict__ Pprod, const float* __restrict__ Hloc,
    float* __restrict__ Hstart) {
  int tid = blockIdx.x * 256 + threadIdx.x;
  int n = tid & 15;
  int d = (tid >> 4) & (D_INNER - 1);
  int b = tid >> 15;
  float h = 0.f;
#pragma unroll
  for (int c = 0; c < NCHUNK; c++) {
    size_t o = ((size_t)((b * NCHUNK + c) * D_INNER) + d) * D_STATE + n;
    Hstart[o] = h;
    h = Pprod[o] * h + Hloc[o];
  }
}

__global__ __launch_bounds__(256) void scan_phase3(
    const bf16* __restrict__ Bm, const bf16* __restrict__ Cm,
    const float* __restrict__ delta, const float* __restrict__ xg,
    const float* __restrict__ A_log, const float* __restrict__ Dp,
    const float* __restrict__ Hstart, bf16* __restrict__ y) {
  int tid = blockIdx.x * 256 + threadIdx.x;
  int n = tid & 15;
  int d = (tid >> 4) & (D_INNER - 1);
  int c = (tid >> 15) & (NCHUNK - 1);
  int b = tid >> 19;
  float A = -__expf(A_log[d * D_STATE + n]);
  float dcoef = Dp[d];
  int s0 = c * CLEN;
  size_t bc = ((size_t)(b * SEQ + s0) * D_INNER + d) * D_STATE + n;
  size_t dB = (size_t)(b * SEQ + s0) * D_INNER + d;
  size_t gB = (size_t)(b * SEQ + s0) * (2 * D_INNER) + d;
  float h = Hstart[((size_t)((b * NCHUNK + c) * D_INNER) + d) * D_STATE + n];
  for (int s = 0; s < CLEN; s++) {
    float bm = (float)Bm[bc + (size_t)s * (D_INNER * D_STATE)];
    float cm = (float)Cm[bc + (size_t)s * (D_INNER * D_STATE)];
    float dl = delta[dB + (size_t)s * D_INNER];
    float xp = xg[gB + (size_t)s * (2 * D_INNER)];
    float a = __expf(dl * A);
    h = a * h + (dl * bm) * xp;
    float p = cm * h;
    p += __shfl_xor(p, 1);
    p += __shfl_xor(p, 2);
    p += __shfl_xor(p, 4);
    p += __shfl_xor(p, 8);
    if (n == 0) {
      float gt = xg[gB + D_INNER + (size_t)s * (2 * D_INNER)];
      float sig = 1.f / (1.f + __expf(-gt));
      float yv = (p + dcoef * xp) * (gt * sig);
      y[dB + (size_t)s * D_INNER] = (bf16)yv;
    }
  }
}

// ------------------------------------------------------------------- MFMA GEMM
// C[M,N] = A[M,K] bf16 row-major * Bt[N,K]^T bf16 + bias, fused epilogue.
// m97 structure: global_load_lds width=16 into unpadded 128x32 LDS tiles.
// Grid: x = M-tiles (fastest) so concurrent blocks share the same B slice.
enum { EPI_PLAIN = 0, EPI_DT = 1, EPI_BF16 = 2, EPI_ADD = 3, EPI_GELU = 4 };

template <int EPI>
__global__ __launch_bounds__(256) void gemm_bf16(
    const bf16* __restrict__ A, const bf16* __restrict__ Bt,
    const float* __restrict__ bias, const float* __restrict__ extra,
    void* __restrict__ outv, int M, int N, int K) {
  __shared__ bf16 As[128 * 32];  // unpadded: required by global_load_lds lane order
  __shared__ bf16 Bs[128 * 32];
  int t = threadIdx.x;
  int lane = t & 63, wid = t >> 6;
  int wm = wid & 1, wn = wid >> 1;   // 2x2 waves, each 64x64
  int l16 = lane & 15, quad = lane >> 4;
  int m0 = blockIdx.x * 128, n0 = blockIdx.y * 128;

  // staging: each call stages 16 rows x 64B per wave; lane -> (row=lane>>2, 16B col=lane&3)
  int srow = wid * 16 + (lane >> 2);
  int scol = (lane & 3) * 8;  // bf16 offset
  const bf16* ga0 = A + (size_t)(m0 + srow) * K + scol;
  const bf16* ga1 = ga0 + (size_t)64 * K;
  const bf16* gb0 = Bt + (size_t)(n0 + srow) * K + scol;
  const bf16* gb1 = gb0 + (size_t)64 * K;
  bf16* lA0 = &As[wid * 512];         // rows 16w..16w+15
  bf16* lA1 = &As[2048 + wid * 512];  // rows 64+16w..
  bf16* lB0 = &Bs[wid * 512];
  bf16* lB1 = &Bs[2048 + wid * 512];

  f32x4 acc[4][4] = {};
  for (int k0 = 0; k0 < K; k0 += 32) {
    __syncthreads();  // previous iter's ds_reads done before overwrite
    GLOAD_LDS16(ga0 + k0, lA0);
    GLOAD_LDS16(ga1 + k0, lA1);
    GLOAD_LDS16(gb0 + k0, lB0);
    GLOAD_LDS16(gb1 + k0, lB1);
    __syncthreads();  // drains vmcnt -> LDS tiles valid
    bf16x8 af[4], bfr[4];
#pragma unroll
    for (int i = 0; i < 4; i++) {
      af[i]  = *(const bf16x8*)&As[(wm * 64 + i * 16 + l16) * 32 + quad * 8];
      bfr[i] = *(const bf16x8*)&Bs[(wn * 64 + i * 16 + l16) * 32 + quad * 8];
    }
#pragma unroll
    for (int mi = 0; mi < 4; mi++)
#pragma unroll
      for (int ni = 0; ni < 4; ni++)
        acc[mi][ni] = __builtin_amdgcn_mfma_f32_16x16x32_bf16(af[mi], bfr[ni],
                                                              acc[mi][ni], 0, 0, 0);
  }
  // epilogue: D row = quad*4+r, col = l16 (verified m89/m91 layout)
#pragma unroll
  for (int mi = 0; mi < 4; mi++) {
#pragma unroll
    for (int ni = 0; ni < 4; ni++) {
      int col = n0 + wn * 64 + ni * 16 + l16;
      int mrow0 = m0 + wm * 64 + mi * 16 + quad * 4;
#pragma unroll
      for (int r = 0; r < 4; r++) {
        int m = mrow0 + r;
        float v = acc[mi][ni][r] + bias[col];
        size_t o = (size_t)m * N + col;
        if (EPI == EPI_PLAIN) {
          ((float*)outv)[o] = v;
        } else if (EPI == EPI_DT) {
          ((float*)outv)[o] = (1.f / (1.f + __expf(-v))) * 0.099f + 0.001f;
        } else if (EPI == EPI_BF16) {
          ((bf16*)outv)[o] = (bf16)v;
        } else if (EPI == EPI_ADD) {
          ((float*)outv)[o] = v + extra[o];
        } else if (EPI == EPI_GELU) {
          ((bf16*)outv)[o] = (bf16)(0.5f * v * (1.f + erff(v * 0.70710678118f)));
        }
      }
    }
  }
}

// ---------------------------------------------------------------------- launch
extern "C" void kernel_launch(void* const* d_in, const int* in_sizes, int n_in,
                              void* d_out, int out_size, void* d_ws, size_t ws_size,
                              hipStream_t stream) {
  const float* x      = (const float*)d_in[0];
  const float* ln1_g  = (const float*)d_in[1];
  const float* ln1_b  = (const float*)d_in[2];
  const float* W_in   = (const float*)d_in[3];
  const float* b_in   = (const float*)d_in[4];
  const float* conv_w = (const float*)d_in[5];
  const float* conv_b = (const float*)d_in[6];
  const float* A_log  = (const float*)d_in[7];
  const float* W_B    = (const float*)d_in[8];
  const float* b_B    = (const float*)d_in[9];
  const float* W_C    = (const float*)d_in[10];
  const float* b_C    = (const float*)d_in[11];
  const float* Dp     = (const float*)d_in[12];
  const float* W_dt   = (const float*)d_in[13];
  const float* b_dt   = (const float*)d_in[14];
  const float* W_out  = (const float*)d_in[15];
  const float* b_out  = (const float*)d_in[16];
  const float* ln2_g  = (const float*)d_in[17];
  const float* ln2_b  = (const float*)d_in[18];
  const float* W1     = (const float*)d_in[19];
  const float* b1     = (const float*)d_in[20];
  const float* W2     = (const float*)d_in[21];
  const float* b2     = (const float*)d_in[22];
  float* out = (float*)d_out;

  char* ws = (char*)d_ws;
  size_t off = 0;
  auto alloc = [&](size_t bytes) -> void* {
    void* p = ws + off;
    off += (bytes + 255) & ~(size_t)255;
    return p;
  };
  bf16*  xn_bf  = (bf16*)alloc((size_t)NTOK * D_MODEL * 2);
  float* xg     = (float*)alloc((size_t)NTOK * 2 * D_INNER * 4);
  bf16*  xc_bf  = (bf16*)alloc((size_t)NTOK * D_INNER * 2);
  float* delta  = (float*)alloc((size_t)NTOK * D_INNER * 4);
  bf16*  Bm     = (bf16*)alloc((size_t)NTOK * D_INNER * D_STATE * 2);
  bf16*  Cm     = (bf16*)alloc((size_t)NTOK * D_INNER * D_STATE * 2);
  bf16*  y_bf   = (bf16*)alloc((size_t)NTOK * D_INNER * 2);
  float* x2     = (float*)alloc((size_t)NTOK * D_MODEL * 4);
  bf16*  xn2_bf = (bf16*)alloc((size_t)NTOK * D_MODEL * 2);
  bf16*  h1_bf  = (bf16*)alloc((size_t)NTOK * D_FF * 2);
  float* Pprod  = (float*)alloc((size_t)B_SZ * NCHUNK * D_INNER * D_STATE * 4);
  float* Hloc   = (float*)alloc((size_t)B_SZ * NCHUNK * D_INNER * D_STATE * 4);
  float* Hstart = (float*)alloc((size_t)B_SZ * NCHUNK * D_INNER * D_STATE * 4);
  bf16*  wt     = (bf16*)alloc((size_t)D_INNER * (D_INNER * D_STATE) * 2); // reused

  dim3 blk(256);

  // 1. LN1
  ln_kernel<<<NTOK, blk, 0, stream>>>(x, ln1_g, ln1_b, xn_bf);
  // 2. in-projection -> xg (x_proj | gate)
  transpose_bf16_kernel<<<dim3((2 * D_INNER) / 64, D_MODEL / 64), blk, 0, stream>>>(
      W_in, wt, D_MODEL, 2 * D_INNER);
  gemm_bf16<EPI_PLAIN><<<dim3(NTOK / 128, (2 * D_INNER) / 128), blk, 0, stream>>>(
      xn_bf, wt, b_in, nullptr, xg, NTOK, 2 * D_INNER, D_MODEL);
  // 3. causal depthwise conv -> xc
  conv_kernel<<<(NTOK * D_INNER) / 256, blk, 0, stream>>>(xg, conv_w, conv_b, xc_bf);
  // 4. delta
  transpose_bf16_kernel<<<dim3(D_INNER / 64, D_INNER / 64), blk, 0, stream>>>(
      W_dt, wt, D_INNER, D_INNER);
  gemm_bf16<EPI_DT><<<dim3(NTOK / 128, D_INNER / 128), blk, 0, stream>>>(
      xc_bf, wt, b_dt, nullptr, delta, NTOK, D_INNER, D_INNER);
  // 5. B projection
  transpose_bf16_kernel<<<dim3((D_INNER * D_STATE) / 64, D_INNER / 64), blk, 0, stream>>>(
      W_B, wt, D_INNER, D_INNER * D_STATE);
  gemm_bf16<EPI_BF16><<<dim3(NTOK / 128, (D_INNER * D_STATE) / 128), blk, 0, stream>>>(
      xc_bf, wt, b_B, nullptr, Bm, NTOK, D_INNER * D_STATE, D_INNER);
  // 6. C projection (reuse wt after GEMM_B — stream-ordered)
  transpose_bf16_kernel<<<dim3((D_INNER * D_STATE) / 64, D_INNER / 64), blk, 0, stream>>>(
      W_C, wt, D_INNER, D_INNER * D_STATE);
  gemm_bf16<EPI_BF16><<<dim3(NTOK / 128, (D_INNER * D_STATE) / 128), blk, 0, stream>>>(
      xc_bf, wt, b_C, nullptr, Cm, NTOK, D_INNER * D_STATE, D_INNER);
  // 7. selective scan, chunk-parallel (fused +Dp*x_proj and *silu(gate))
  scan_phase1<<<(B_SZ * NCHUNK * D_INNER * D_STATE) / 256, blk, 0, stream>>>(
      Bm, delta, xg, A_log, Pprod, Hloc);
  scan_phase2<<<(B_SZ * D_INNER * D_STATE) / 256, blk, 0, stream>>>(
      Pprod, Hloc, Hstart);
  scan_phase3<<<(B_SZ * NCHUNK * D_INNER * D_STATE) / 256, blk, 0, stream>>>(
      Bm, Cm, delta, xg, A_log, Dp, Hstart, y_bf);
  // 8. out projection + residual
  transpose_bf16_kernel<<<dim3(D_MODEL / 64, D_INNER / 64), blk, 0, stream>>>(
      W_out, wt, D_INNER, D_MODEL);
  gemm_bf16<EPI_ADD><<<dim3(NTOK / 128, D_MODEL / 128), blk, 0, stream>>>(
      y_bf, wt, b_out, x, x2, NTOK, D_MODEL, D_INNER);
  // 9. LN2
  ln_kernel<<<NTOK, blk, 0, stream>>>(x2, ln2_g, ln2_b, xn2_bf);
  // 10. FFN up + exact GELU
  transpose_bf16_kernel<<<dim3(D_FF / 64, D_MODEL / 64), blk, 0, stream>>>(
      W1, wt, D_MODEL, D_FF);
  gemm_bf16<EPI_GELU><<<dim3(NTOK / 128, D_FF / 128), blk, 0, stream>>>(
      xn2_bf, wt, b1, nullptr, h1_bf, NTOK, D_FF, D_MODEL);
  // 11. FFN down + residual -> out
  transpose_bf16_kernel<<<dim3(D_MODEL / 64, D_FF / 64), blk, 0, stream>>>(
      W2, wt, D_FF, D_MODEL);
  gemm_bf16<EPI_ADD><<<dim3(NTOK / 128, D_MODEL / 128), blk, 0, stream>>>(
      h1_bf, wt, b2, x2, out, NTOK, D_MODEL, D_FF);
}